// Round 8
// baseline (403.912 us; speedup 1.0000x reference)
//
#include <hip/hip_runtime.h>
#include <hip/hip_bf16.h>

typedef __attribute__((ext_vector_type(8))) short short8;
typedef __attribute__((ext_vector_type(4))) float f32x4;

#define BM 128
#define BN 128
#define BK 64
#define KDIM 7168
#define NDIM 18432
#define SN 56            // KDIM/128 scale cols
#define NTK 112          // KDIM/BK

static __device__ __forceinline__ short bfb(float f) {
    __hip_bfloat16 h = __float2bfloat16(f);
    return __builtin_bit_cast(short, h);
}

// ---- pre-kernel: A fp32 -> bf16, tile-major, inverse-XOR-swizzled so the
// GEMM can global_load_lds it linearly and read with the XOR formula.
// unit g = ((mt*NTK + kt)*1024 + r*8 + slot); content = A[mt*128+r][kt*64 + (slot^(r&7))*8 .. +8)
extern "C" __global__ void __launch_bounds__(256)
a_permute(const float* __restrict__ A, __hip_bfloat16* __restrict__ Abt, int nunits) {
    int g = blockIdx.x * blockDim.x + threadIdx.x;
    if (g >= nunits) return;
    int u    = g & 1023;
    int t    = g >> 10;
    int ktt  = t % NTK;
    int mt   = t / NTK;
    int r    = u >> 3;
    int slot = u & 7;
    int row  = mt * BM + r;
    int col  = ktt * BK + ((slot ^ (r & 7)) << 3);
    const float* p = A + (size_t)row * KDIM + col;
    f32x4 v0 = *(const f32x4*)p;
    f32x4 v1 = *(const f32x4*)(p + 4);
    short8 o;
#pragma unroll
    for (int j = 0; j < 4; ++j) { o[j] = bfb(v0[j]); o[j + 4] = bfb(v1[j]); }
    *(short8*)(Abt + (size_t)g * 8) = o;
}

// AMODE 1: A via global_load_lds from pre-permuted Abt.
// AMODE 0: fallback, A fp32 reg-staged.
template <int AMODE>
__global__ void __launch_bounds__(512, 2)
fp8lin_gemm(const float* __restrict__ A,          // [M][K] fp32
            const char*  __restrict__ Abt,        // pre-permuted bf16 tiles (ws)
            const float* __restrict__ W,          // [N][K] fp32
            const float* __restrict__ S,          // [N/128][K/128]
            float* __restrict__ C,                // [M][N]
            int M)
{
    const int ntile_m = M / BM;            // 4
    const int ntile_n = NDIM / BN;         // 144
    const int nwg = ntile_m * ntile_n;     // 576

    // chunked XCD swizzle; m-minor so the 4 blocks sharing a W panel sit on
    // the same XCD's L2.
    int orig = (int)blockIdx.x;
    int q = nwg >> 3;
    int lid = (orig & 7) * q + (orig >> 3);

    const int tm = lid % ntile_m;
    const int tn = lid / ntile_m;
    const int m0 = tm * BM;
    const int n0 = tn * BN;

    const int tid  = threadIdx.x;
    const int lane = tid & 63;
    const int wid  = tid >> 6;      // 8 waves: 2(K-split) x 2(M) x 2(N)
    const int kk   = wid >> 2;      // K-half owned by this wave
    const int wm   = (wid >> 1) & 1;
    const int wn   = wid & 1;

    __shared__ char ldsA[2][BM * BK * 2];   // bf16 A tiles, 16 KiB each
    __shared__ char ldsW[2][BN * BK * 2];   // bf16 dequant W tiles, 16 KiB each

    // W staging geometry (and A in AMODE 0): unit u = c*512+tid;
    // r = u>>3, slot = u&7; XOR-swizzled LDS byte.
    int st_r[2], st_sl[2], st_byte[2];
#pragma unroll
    for (int c = 0; c < 2; ++c) {
        int u = c * 512 + tid;
        int r  = u >> 3;
        int sl = u & 7;
        st_r[c]    = r;
        st_sl[c]   = sl;
        st_byte[c] = r * (BK * 2) + ((sl ^ (r & 7)) << 4);
    }

    const float* Afp = A + (size_t)m0 * KDIM;
    const float* Wb  = W + (size_t)n0 * KDIM;

    f32x4 rw[2][2];        // W fp32 staging (distance-2 prefetch)
    f32x4 rafp[2][2];      // A fp32 staging (AMODE 0 only)

    auto AGL = [&](int kt_, int buf) {   // async A: global -> LDS, 2 insts/wave
        const char* src = Abt + (((size_t)(tm * NTK + kt_)) << 14);
#pragma unroll
        for (int c = 0; c < 2; ++c) {
            int ub = wid * 128 + c * 64;
            __builtin_amdgcn_global_load_lds(
                (const __attribute__((address_space(1))) void*)(src + (size_t)(ub + lane) * 16),
                (__attribute__((address_space(3))) void*)(&ldsA[buf][ub * 16]),
                16, 0, 0);
        }
    };

    auto WLD = [&](int kt_) {            // W fp32 -> regs (4 x dwordx4)
        const int kof = kt_ * BK;
#pragma unroll
        for (int c = 0; c < 2; ++c) {
            const float* pw = Wb + (size_t)st_r[c] * KDIM + kof + st_sl[c] * 8;
            rw[c][0] = *(const f32x4*)pw;
            rw[c][1] = *(const f32x4*)(pw + 4);
        }
    };

    auto ALD = [&](int kt_) {            // AMODE 0: A fp32 -> regs
        const int kof = kt_ * BK;
#pragma unroll
        for (int c = 0; c < 2; ++c) {
            const float* pa = Afp + (size_t)st_r[c] * KDIM + kof + st_sl[c] * 8;
            rafp[c][0] = *(const f32x4*)pa;
            rafp[c][1] = *(const f32x4*)(pa + 4);
        }
    };

    auto WRITES = [&](int buf, float s) {  // dequant convert + ds_write
#pragma unroll
        for (int c = 0; c < 2; ++c) {
            short8 vw;
#pragma unroll
            for (int j = 0; j < 4; ++j) {
                vw[j]     = bfb(rw[c][0][j] * s);
                vw[j + 4] = bfb(rw[c][1][j] * s);
            }
            *(short8*)(&ldsW[buf][st_byte[c]]) = vw;
            if (AMODE == 0) {
                short8 va;
#pragma unroll
                for (int j = 0; j < 4; ++j) {
                    va[j]     = bfb(rafp[c][0][j]);
                    va[j + 4] = bfb(rafp[c][1][j]);
                }
                *(short8*)(&ldsA[buf][st_byte[c]]) = va;
            }
        }
    };

    f32x4 acc[4][4];
#pragma unroll
    for (int i = 0; i < 4; ++i)
#pragma unroll
        for (int j = 0; j < 4; ++j)
            acc[i][j] = f32x4{0.f, 0.f, 0.f, 0.f};

    const int l15 = lane & 15;
    const int lq  = lane >> 4;

    // K-split COMPUTE: this wave handles only chunks [kk*4 .. kk*4+3] of the
    // 8 16B chunks in BK=64 -> single MFMA pass, 8 ds_read for 16 MFMA.
    auto COMPUTE = [&](int buf) {
        const char* la = ldsA[buf];
        const char* lb = ldsW[buf];
        const int kc = kk * 4 + lq;
        short8 af[4], bq[4];
#pragma unroll
        for (int i = 0; i < 4; ++i) {
            int r = wm * 64 + i * 16 + l15;
            af[i] = *(const short8*)(la + r * (BK * 2) + ((kc ^ (r & 7)) << 4));
        }
#pragma unroll
        for (int j = 0; j < 4; ++j) {
            int r = wn * 64 + j * 16 + l15;
            bq[j] = *(const short8*)(lb + r * (BK * 2) + ((kc ^ (r & 7)) << 4));
        }
#pragma unroll
        for (int i = 0; i < 4; ++i)
#pragma unroll
            for (int j = 0; j < 4; ++j)
                acc[i][j] = __builtin_amdgcn_mfma_f32_16x16x32_bf16(af[i], bq[j], acc[i][j], 0, 0, 0);
    };

    const float* Srow = S + (size_t)tn * SN;

    // ---- prologue
    if (AMODE) AGL(0, 0); else ALD(0);
    WLD(0);
    WRITES(0, Srow[0]);
    if (AMODE == 0) ALD(1);
    WLD(1);
    __syncthreads();

    // ---- main loop: plain 2-phase double-buffer, distance-2 W prefetch
    for (int kt = 0; kt < NTK; ++kt) {
        const int cur = kt & 1;
        const int nxt = cur ^ 1;
        if (AMODE && kt + 1 < NTK) AGL(kt + 1, nxt);
        COMPUTE(cur);
        if (kt + 1 < NTK) {
            WRITES(nxt, Srow[(kt + 1) >> 1]);
            if (kt + 2 < NTK) { if (AMODE == 0) ALD(kt + 2); WLD(kt + 2); }
        }
        __syncthreads();
    }

    // ---- K-split reduction: kk=1 waves dump acc to LDS, kk=0 waves add.
    // Region per (wm,wn): 16 KiB. Lane layout: q-th f32x4 at q*1024 + lane*16.
    {
        const int rg = wm * 2 + wn;
        char* base = (rg < 2) ? &ldsA[rg][0] : &ldsW[rg - 2][0];
        if (kk == 1) {
#pragma unroll
            for (int i = 0; i < 4; ++i)
#pragma unroll
                for (int j = 0; j < 4; ++j)
                    *(f32x4*)(base + (i * 4 + j) * 1024 + lane * 16) = acc[i][j];
        }
        __syncthreads();
        if (kk == 0) {
#pragma unroll
            for (int i = 0; i < 4; ++i)
#pragma unroll
                for (int j = 0; j < 4; ++j) {
                    f32x4 o = *(const f32x4*)(base + (i * 4 + j) * 1024 + lane * 16);
                    acc[i][j] += o;
                }
            // epilogue: C/D layout col=lane&15, row=(lane>>4)*4+r
            float* Cb = C + (size_t)(m0 + wm * 64) * NDIM + (n0 + wn * 64);
            const int crow = lq * 4;
#pragma unroll
            for (int i = 0; i < 4; ++i) {
#pragma unroll
                for (int r = 0; r < 4; ++r) {
                    float* Cr = Cb + (size_t)(i * 16 + crow + r) * NDIM + l15;
#pragma unroll
                    for (int j = 0; j < 4; ++j)
                        Cr[j * 16] = acc[i][j][r];
                }
            }
        }
    }
}

extern "C" void kernel_launch(void* const* d_in, const int* in_sizes, int n_in,
                              void* d_out, int out_size, void* d_ws, size_t ws_size,
                              hipStream_t stream) {
    const float* inp = (const float*)d_in[0];   // [1,512,7168] fp32
    const float* w   = (const float*)d_in[1];   // [18432,7168] fp32
    const float* s   = (const float*)d_in[2];   // [144,56] fp32
    float* out       = (float*)d_out;           // [1,512,18432] fp32

    int M = in_sizes[0] / KDIM;                 // 512
    int grid = (M / BM) * (NDIM / BN);          // 576
    int nunits = (M / BM) * NTK * 1024;
    size_t need = (size_t)nunits * 16;

    if (ws_size >= need) {
        __hip_bfloat16* abt = (__hip_bfloat16*)d_ws;
        hipLaunchKernelGGL(a_permute, dim3((nunits + 255) / 256), dim3(256), 0, stream,
                           inp, abt, nunits);
        hipLaunchKernelGGL((fp8lin_gemm<1>), dim3(grid), dim3(512), 0, stream,
                           inp, (const char*)abt, w, s, out, M);
    } else {
        hipLaunchKernelGGL((fp8lin_gemm<0>), dim3(grid), dim3(512), 0, stream,
                           inp, (const char*)nullptr, w, s, out, M);
    }
}

// Round 11
// 316.688 us; speedup vs baseline: 1.2754x; 1.2754x over previous
//
#include <hip/hip_runtime.h>
#include <hip/hip_bf16.h>

typedef __attribute__((ext_vector_type(8))) short short8;
typedef __attribute__((ext_vector_type(4))) float f32x4;

#define BM 128
#define BN 128
#define BK 32
#define KDIM 7168
#define NDIM 18432
#define SN 56            // KDIM/128 scale cols
#define NT32 224         // KDIM/BK
#define SPLITK 2
#define STEPS (NT32 / SPLITK)   // 112 per block

static __device__ __forceinline__ short bfb(float f) {
    __hip_bfloat16 h = __float2bfloat16(f);
    return __builtin_bit_cast(short, h);
}

// ---- pre-kernel: A fp32 -> bf16, BK=32-tile-major, inverse-XOR-swizzled so
// the GEMM stages it with global_load_lds (linear dest) and reads with XOR.
// unit g: u=g&511, t=g>>9, kt=t%NT32, mt=t/NT32, r=u>>2, slot=u&3
// content = A[mt*128+r][kt*32 + ((slot^(r&3))*8) .. +8)
extern "C" __global__ void __launch_bounds__(256)
a_permute(const float* __restrict__ A, __hip_bfloat16* __restrict__ Abt, int nunits) {
    int g = blockIdx.x * blockDim.x + threadIdx.x;
    if (g >= nunits) return;
    int u    = g & 511;
    int t    = g >> 9;
    int ktt  = t % NT32;
    int mt   = t / NT32;
    int r    = u >> 2;
    int slot = u & 3;
    int row  = mt * BM + r;
    int col  = ktt * BK + ((slot ^ (r & 3)) << 3);
    const float* p = A + (size_t)row * KDIM + col;
    f32x4 v0 = *(const f32x4*)p;
    f32x4 v1 = *(const f32x4*)(p + 4);
    short8 o;
#pragma unroll
    for (int j = 0; j < 4; ++j) { o[j] = bfb(v0[j]); o[j + 4] = bfb(v1[j]); }
    *(short8*)(Abt + (size_t)g * 8) = o;
}

// AMODE 1: A via global_load_lds from pre-permuted Abt.  AMODE 0: reg-staged.
// Split-K=2 over blockIdx.y; partial sums atomicAdd'ed into zeroed C.
template <int AMODE>
__global__ void __launch_bounds__(512, 8)
fp8lin_gemm(const float* __restrict__ A,          // [M][K] fp32
            const char*  __restrict__ Abt,        // pre-permuted bf16 tiles (ws)
            const float* __restrict__ W,          // [N][K] fp32
            const float* __restrict__ S,          // [N/128][K/128]
            float* __restrict__ C,                // [M][N], pre-zeroed
            int M)
{
    const int ntile_m = M / BM;            // 4
    const int ntile_n = NDIM / BN;         // 144
    const int nwg = ntile_m * ntile_n;     // 576

    // chunked XCD swizzle; m-minor so the 4 blocks sharing a W panel sit on
    // the same XCD's L2.
    int orig = (int)blockIdx.x;
    int q = nwg >> 3;
    int lid = (orig & 7) * q + (orig >> 3);

    const int tm = lid % ntile_m;
    const int tn = lid / ntile_m;
    const int kh = blockIdx.y;             // K-half
    const int m0 = tm * BM;
    const int n0 = tn * BN;
    const int g0 = kh * STEPS;             // first global K-step

    const int tid  = threadIdx.x;
    const int lane = tid & 63;
    const int wid  = tid >> 6;      // 8 waves: 2(M) x 4(N), wave tile 64x32
    const int wm   = wid >> 2;
    const int wn   = wid & 3;

    __shared__ char ldsA[2][BM * BK * 2];   // bf16, 8 KiB each
    __shared__ char ldsW[2][BN * BK * 2];   // bf16, 8 KiB each  (32 KiB total)

    // W staging: one 16B unit per thread: r=tid>>2, sl=tid&3.
    // LDS write is LINEAR (tid*16); the XOR lives in the global source col.
    const int st_r  = tid >> 2;
    const int st_sl = tid & 3;
    const int st_gc = (st_sl ^ (st_r & 3)) << 3;   // global col offset 0..24

    const float* Afp = A + (size_t)m0 * KDIM;
    const float* Wb  = W + (size_t)n0 * KDIM + (size_t)st_r * KDIM + st_gc;

    f32x4 rw[2];           // W fp32 staging (one unit = 32B)
    f32x4 rafp[2];         // A fp32 staging (AMODE 0 only)

    auto AGL = [&](int gstep, int buf) {   // async A: global -> LDS, 1 inst/wave
        const char* src = Abt + (((size_t)(tm * NT32 + gstep)) << 13);
        int ub = wid * 64 + lane;
        __builtin_amdgcn_global_load_lds(
            (const __attribute__((address_space(1))) void*)(src + (size_t)ub * 16),
            (__attribute__((address_space(3))) void*)(&ldsA[buf][ub * 16]),
            16, 0, 0);
    };

    auto WLD = [&](int gstep) {            // W fp32 -> regs (2 x dwordx4)
        const float* pw = Wb + gstep * BK;
        rw[0] = *(const f32x4*)pw;
        rw[1] = *(const f32x4*)(pw + 4);
    };

    auto ALD = [&](int gstep) {            // AMODE 0: A fp32 -> regs
        const float* pa = Afp + (size_t)st_r * KDIM + gstep * BK + st_gc;
        rafp[0] = *(const f32x4*)pa;
        rafp[1] = *(const f32x4*)(pa + 4);
    };

    auto WRITES = [&](int buf, float s) {  // dequant convert + 1 linear ds_write
        short8 vw;
#pragma unroll
        for (int j = 0; j < 4; ++j) {
            vw[j]     = bfb(rw[0][j] * s);
            vw[j + 4] = bfb(rw[1][j] * s);
        }
        *(short8*)(&ldsW[buf][tid * 16]) = vw;
        if (AMODE == 0) {
            short8 va;
#pragma unroll
            for (int j = 0; j < 4; ++j) {
                va[j]     = bfb(rafp[0][j]);
                va[j + 4] = bfb(rafp[1][j]);
            }
            *(short8*)(&ldsA[buf][tid * 16]) = va;
        }
    };

    f32x4 acc[4][2];
#pragma unroll
    for (int i = 0; i < 4; ++i)
#pragma unroll
        for (int j = 0; j < 2; ++j)
            acc[i][j] = f32x4{0.f, 0.f, 0.f, 0.f};

    const int l15 = lane & 15;
    const int lq  = lane >> 4;      // 16B chunk 0..3 along BK=32

    auto COMPUTE = [&](int buf) {
        const char* la = ldsA[buf];
        const char* lb = ldsW[buf];
        short8 af[4], bq[2];
#pragma unroll
        for (int i = 0; i < 4; ++i) {
            int r = wm * 64 + i * 16 + l15;
            af[i] = *(const short8*)(la + r * (BK * 2) + (((lq ^ (r & 3))) << 4));
        }
#pragma unroll
        for (int j = 0; j < 2; ++j) {
            int r = wn * 32 + j * 16 + l15;
            bq[j] = *(const short8*)(lb + r * (BK * 2) + (((lq ^ (r & 3))) << 4));
        }
#pragma unroll
        for (int i = 0; i < 4; ++i)
#pragma unroll
            for (int j = 0; j < 2; ++j)
                acc[i][j] = __builtin_amdgcn_mfma_f32_16x16x32_bf16(af[i], bq[j], acc[i][j], 0, 0, 0);
    };

    const float* Srow = S + (size_t)tn * SN;   // scale col for step g: g>>2

    // ---- prologue (local steps 0,1 -> global g0, g0+1)
    if (AMODE) AGL(g0, 0); else ALD(g0);
    WLD(g0);
    WRITES(0, Srow[g0 >> 2]);
    if (AMODE == 0) ALD(g0 + 1);
    WLD(g0 + 1);
    __syncthreads();

    // ---- main loop: 2-phase double-buffer, distance-2 W prefetch
    for (int kt = 0; kt < STEPS; ++kt) {
        const int cur = kt & 1;
        const int nxt = cur ^ 1;
        if (AMODE && kt + 1 < STEPS) AGL(g0 + kt + 1, nxt);
        COMPUTE(cur);
        if (kt + 1 < STEPS) {
            WRITES(nxt, Srow[(g0 + kt + 1) >> 2]);
            if (kt + 2 < STEPS) { if (AMODE == 0) ALD(g0 + kt + 2); WLD(g0 + kt + 2); }
        }
        __syncthreads();
    }

    // ---- epilogue: C/D layout col=lane&15, row=(lane>>4)*4+r; atomic K-merge
    float* Cb = C + (size_t)(m0 + wm * 64) * NDIM + (n0 + wn * 32);
    const int crow = lq * 4;
#pragma unroll
    for (int i = 0; i < 4; ++i) {
#pragma unroll
        for (int r = 0; r < 4; ++r) {
            float* Cr = Cb + (size_t)(i * 16 + crow + r) * NDIM + l15;
#pragma unroll
            for (int j = 0; j < 2; ++j)
                atomicAdd(&Cr[j * 16], acc[i][j][r]);
        }
    }
}

extern "C" void kernel_launch(void* const* d_in, const int* in_sizes, int n_in,
                              void* d_out, int out_size, void* d_ws, size_t ws_size,
                              hipStream_t stream) {
    const float* inp = (const float*)d_in[0];   // [1,512,7168] fp32
    const float* w   = (const float*)d_in[1];   // [18432,7168] fp32
    const float* s   = (const float*)d_in[2];   // [144,56] fp32
    float* out       = (float*)d_out;           // [1,512,18432] fp32

    int M = in_sizes[0] / KDIM;                 // 512
    dim3 grid((M / BM) * (NDIM / BN), SPLITK);  // 576 x 2
    int nunits = (M / BM) * NT32 * 512;
    size_t need = (size_t)nunits * 16;

    hipMemsetAsync(out, 0, (size_t)out_size * sizeof(float), stream);

    if (ws_size >= need) {
        __hip_bfloat16* abt = (__hip_bfloat16*)d_ws;
        hipLaunchKernelGGL(a_permute, dim3((nunits + 255) / 256), dim3(256), 0, stream,
                           inp, abt, nunits);
        hipLaunchKernelGGL((fp8lin_gemm<1>), grid, dim3(512), 0, stream,
                           inp, (const char*)abt, w, s, out, M);
    } else {
        hipLaunchKernelGGL((fp8lin_gemm<0>), grid, dim3(512), 0, stream,
                           inp, (const char*)nullptr, w, s, out, M);
    }
}